// Round 3
// baseline (6298.294 us; speedup 1.0000x reference)
//
#include <hip/hip_runtime.h>
#include <math.h>

#define NN 100000
#define NE 1600000
#define FIN 500
#define HID 256
#define NC 40
#define KIT 5
#define L1P 3.0f
#define GAM 0.25f
#define BET 2.0f
#define OMG 0.75f   // 1 - gamma

// ---------------- CSR build ----------------
__global__ void k_hist(const int* __restrict__ s, const int* __restrict__ d, int* c) {
    int e = blockIdx.x * 256 + threadIdx.x;
    if (e < NE) { atomicAdd(&c[s[e]], 1); atomicAdd(&c[d[e]], 1); }
}

__global__ void k_scan1(const int* __restrict__ cnt, int* rp, int* bs) {
    __shared__ int sm[1024];
    int i = blockIdx.x * 1024 + threadIdx.x;
    int v = (i < NN) ? cnt[i] : 0;
    sm[threadIdx.x] = v;
    __syncthreads();
    for (int off = 1; off < 1024; off <<= 1) {
        int t = (threadIdx.x >= off) ? sm[threadIdx.x - off] : 0;
        __syncthreads();
        sm[threadIdx.x] += t;
        __syncthreads();
    }
    if (i < NN) rp[i] = sm[threadIdx.x] - v;   // exclusive within block
    if (threadIdx.x == 1023) bs[blockIdx.x] = sm[1023];
}

__global__ void k_scan2(int* bs, int nb) {
    if (threadIdx.x == 0 && blockIdx.x == 0) {
        int run = 0;
        for (int j = 0; j < nb; j++) { int t = bs[j]; bs[j] = run; run += t; }
    }
}

__global__ void k_scan3(int* rp, const int* __restrict__ bs) {
    int i = blockIdx.x * 1024 + threadIdx.x;
    if (i < NN) rp[i] += bs[blockIdx.x];
    if (i == 0) rp[NN] = 2 * NE;
}

__global__ void k_dis(const int* __restrict__ cnt, float* __restrict__ dis) {
    int n = blockIdx.x * 256 + threadIdx.x;
    if (n < NN) dis[n] = rsqrtf((float)cnt[n] + 1.0f);
}

// adjacency CSR (col) + incidence CSR (eidx: edge_id<<1 | is_dst)
__global__ void k_fill(const int* __restrict__ s, const int* __restrict__ d,
                       const int* __restrict__ rp, int* cur, int* col, int* eidx) {
    int e = blockIdx.x * 256 + threadIdx.x;
    if (e < NE) {
        int a = s[e], b = d[e];
        int p = rp[a] + atomicAdd(&cur[a], 1); col[p] = b; eidx[p] = (e << 1);
        int q = rp[b] + atomicAdd(&cur[b], 1); col[q] = a; eidx[q] = (e << 1) | 1;
    }
}

// ---------------- MLP ----------------
// h1 = relu(x @ W1); fp32 tiled GEMM, 128x128 tile, BK=8, 8x8 microtile
__global__ __launch_bounds__(256) void k_gemm1(const float* __restrict__ X,
                                               const float* __restrict__ W1,
                                               float* __restrict__ H1) {
    __shared__ float As[8][128];
    __shared__ float Bs[8][128];
    const int t = threadIdx.x;
    const int rblk = blockIdx.x * 128;
    const int cblk = blockIdx.y * 128;
    const int tx = t & 15, ty = t >> 4;
    const int lar = t >> 1, lak = (t & 1) * 4;     // A loader: row, k-offset
    const int lbk = t >> 5, lbc = (t & 31) * 4;    // B loader: k, col
    float acc[8][8];
    #pragma unroll
    for (int i = 0; i < 8; i++)
        #pragma unroll
        for (int j = 0; j < 8; j++) acc[i][j] = 0.f;

    for (int k0 = 0; k0 < FIN; k0 += 8) {
        float4 av = make_float4(0.f, 0.f, 0.f, 0.f);
        int row = rblk + lar;
        if (row < NN) {
            if (k0 + lak + 4 <= FIN) {
                av = *(const float4*)(X + (size_t)row * FIN + k0 + lak);
            } else {
                float tv[4] = {0.f, 0.f, 0.f, 0.f};
                #pragma unroll
                for (int j = 0; j < 4; j++)
                    if (k0 + lak + j < FIN) tv[j] = X[(size_t)row * FIN + k0 + lak + j];
                av = make_float4(tv[0], tv[1], tv[2], tv[3]);
            }
        }
        As[lak + 0][lar] = av.x; As[lak + 1][lar] = av.y;
        As[lak + 2][lar] = av.z; As[lak + 3][lar] = av.w;

        float4 bv = make_float4(0.f, 0.f, 0.f, 0.f);
        if (k0 + lbk < FIN) bv = *(const float4*)(W1 + (size_t)(k0 + lbk) * HID + cblk + lbc);
        *(float4*)&Bs[lbk][lbc] = bv;
        __syncthreads();

        #pragma unroll
        for (int kk = 0; kk < 8; kk++) {
            float aF[8], bF[8];
            *(float4*)&aF[0] = *(const float4*)&As[kk][ty * 4];
            *(float4*)&aF[4] = *(const float4*)&As[kk][64 + ty * 4];
            *(float4*)&bF[0] = *(const float4*)&Bs[kk][tx * 4];
            *(float4*)&bF[4] = *(const float4*)&Bs[kk][64 + tx * 4];
            #pragma unroll
            for (int i = 0; i < 8; i++)
                #pragma unroll
                for (int j = 0; j < 8; j++)
                    acc[i][j] = fmaf(aF[i], bF[j], acc[i][j]);
        }
        __syncthreads();
    }

    #pragma unroll
    for (int i = 0; i < 8; i++) {
        int row = rblk + ((i < 4) ? (ty * 4 + i) : (64 + ty * 4 + (i - 4)));
        if (row < NN) {
            float4 v0, v1;
            v0.x = fmaxf(acc[i][0], 0.f); v0.y = fmaxf(acc[i][1], 0.f);
            v0.z = fmaxf(acc[i][2], 0.f); v0.w = fmaxf(acc[i][3], 0.f);
            v1.x = fmaxf(acc[i][4], 0.f); v1.y = fmaxf(acc[i][5], 0.f);
            v1.z = fmaxf(acc[i][6], 0.f); v1.w = fmaxf(acc[i][7], 0.f);
            *(float4*)(H1 + (size_t)row * HID + cblk + tx * 4) = v0;
            *(float4*)(H1 + (size_t)row * HID + cblk + 64 + tx * 4) = v1;
        }
    }
}

// hh = h1 @ W2 ; also xc = hh. Wave per node, lanes = classes.
__global__ __launch_bounds__(256) void k_gemm2(const float* __restrict__ H1,
                                               const float* __restrict__ W2,
                                               float* __restrict__ hh, float* __restrict__ xc) {
    __shared__ float w2s[HID * NC];   // 40 KB
    for (int i = threadIdx.x; i < HID * NC; i += 256) w2s[i] = W2[i];
    __syncthreads();
    int wave = threadIdx.x >> 6, lane = threadIdx.x & 63;
    int n = blockIdx.x * 4 + wave;
    if (n >= NN) return;
    if (lane < NC) {
        const float* hr = H1 + (size_t)n * HID;
        float acc = 0.f;
        #pragma unroll 4
        for (int k = 0; k < HID; k += 4) {
            float4 h4 = *(const float4*)(hr + k);
            acc = fmaf(h4.x, w2s[(k + 0) * NC + lane], acc);
            acc = fmaf(h4.y, w2s[(k + 1) * NC + lane], acc);
            acc = fmaf(h4.z, w2s[(k + 2) * NC + lane], acc);
            acc = fmaf(h4.w, w2s[(k + 3) * NC + lane], acc);
        }
        hh[(size_t)n * NC + lane] = acc;
        xc[(size_t)n * NC + lane] = acc;
    }
}

// ---------------- iteration kernels ----------------
// Fused: y = gamma*hh + omega*dis*(dis*xc + sum_nbr dis_c*xc_c);  xbar = y - gamma*dis*S_prev
__global__ __launch_bounds__(256) void k_ynew(const int* __restrict__ rp, const int* __restrict__ col,
                                              const float* __restrict__ dis, const float* __restrict__ xc,
                                              const float* __restrict__ hh, const float* __restrict__ S,
                                              float* __restrict__ y, float* __restrict__ xbar) {
    int wave = threadIdx.x >> 6, lane = threadIdx.x & 63;
    int n = blockIdx.x * 4 + wave;
    if (n >= NN) return;
    int s = rp[n], e = rp[n + 1];
    if (lane < NC) {
        size_t base = (size_t)n * NC + lane;
        float dn = dis[n];
        float acc = dn * xc[base];                 // self-loop term (dis^2*xc, dn factored out)
        for (int p = s; p < e; p++) {
            int c = col[p];
            acc = fmaf(dis[c], xc[(size_t)c * NC + lane], acc);
        }
        float yv = GAM * hh[base] + OMG * dn * acc;
        y[base] = yv;
        xbar[base] = yv - GAM * dn * S[base];
    }
}

// z = prox_L21(z + beta*inc(x_bar)); edge-centric, no atomics
__global__ __launch_bounds__(256) void k_zup(const int* __restrict__ src, const int* __restrict__ dst,
                                             const float* __restrict__ dis, const float* __restrict__ xb,
                                             float* __restrict__ z, int use_z) {
    int e = blockIdx.x * 256 + threadIdx.x;
    if (e >= NE) return;
    int a = src[e], b = dst[e];
    float da = dis[a], db = dis[b];
    const float* xa = xb + (size_t)a * NC;
    const float* xv = xb + (size_t)b * NC;
    float* zr = z + (size_t)e * NC;
    float zb[NC];
    float n2 = 0.f;
    #pragma unroll
    for (int c4 = 0; c4 < NC; c4 += 4) {
        float4 xa4 = *(const float4*)(xa + c4);
        float4 xb4 = *(const float4*)(xv + c4);
        float4 z4 = use_z ? *(const float4*)(zr + c4) : make_float4(0.f, 0.f, 0.f, 0.f);
        float v;
        v = z4.x + BET * (da * xa4.x - db * xb4.x); zb[c4 + 0] = v; n2 += v * v;
        v = z4.y + BET * (da * xa4.y - db * xb4.y); zb[c4 + 1] = v; n2 += v * v;
        v = z4.z + BET * (da * xa4.z - db * xb4.z); zb[c4 + 2] = v; n2 += v * v;
        v = z4.w + BET * (da * xa4.w - db * xb4.w); zb[c4 + 3] = v; n2 += v * v;
    }
    float rn = sqrtf(n2);
    float scale = (rn > L1P) ? (L1P / rn) : 1.0f;
    #pragma unroll
    for (int c4 = 0; c4 < NC; c4 += 4)
        *(float4*)(zr + c4) = make_float4(zb[c4] * scale, zb[c4 + 1] * scale,
                                          zb[c4 + 2] * scale, zb[c4 + 3] * scale);
}

// Fused: S[n] = sum_{p in incidence} sign_p * z[eid_p];  xc = y - gamma*dis*S
__global__ __launch_bounds__(256) void k_scx(const int* __restrict__ rp, const int* __restrict__ eidx,
                                             const float* __restrict__ z, const float* __restrict__ y,
                                             const float* __restrict__ dis,
                                             float* __restrict__ S, float* __restrict__ xc) {
    int wave = threadIdx.x >> 6, lane = threadIdx.x & 63;
    int n = blockIdx.x * 4 + wave;
    if (n >= NN) return;
    int s = rp[n], e = rp[n + 1];
    if (lane < NC) {
        float acc = 0.f;
        for (int p = s; p < e; p++) {
            int pk = eidx[p];
            float v = z[(size_t)(pk >> 1) * NC + lane];
            acc += (pk & 1) ? -v : v;
        }
        size_t base = (size_t)n * NC + lane;
        S[base] = acc;
        xc[base] = y[base] - GAM * dis[n] * acc;
    }
}

__global__ __launch_bounds__(256) void k_lsm(const float* __restrict__ xc, float* __restrict__ out) {
    int wave = threadIdx.x >> 6, lane = threadIdx.x & 63;
    int n = blockIdx.x * 4 + wave;
    if (n >= NN) return;
    float v = (lane < NC) ? xc[(size_t)n * NC + lane] : -INFINITY;
    float m = v;
    #pragma unroll
    for (int off = 1; off < 64; off <<= 1) m = fmaxf(m, __shfl_xor(m, off));
    float ex = (lane < NC) ? expf(v - m) : 0.f;
    float ssum = ex;
    #pragma unroll
    for (int off = 1; off < 64; off <<= 1) ssum += __shfl_xor(ssum, off);
    if (lane < NC) out[(size_t)n * NC + lane] = v - m - logf(ssum);
}

// ---------------- launch ----------------
extern "C" void kernel_launch(void* const* d_in, const int* in_sizes, int n_in,
                              void* d_out, int out_size, void* d_ws, size_t ws_size,
                              hipStream_t stream) {
    const float* x  = (const float*)d_in[0];
    const float* W1 = (const float*)d_in[1];
    const float* W2 = (const float*)d_in[2];
    const int* src  = (const int*)d_in[3];
    const int* dst  = (const int*)d_in[4];
    float* out = (float*)d_out;

    char* w = (char*)d_ws;
    auto alloc = [&](size_t bytes) { char* p = w; w += (bytes + 255) & ~(size_t)255; return p; };
    float* dis   = (float*)alloc((size_t)NN * 4);
    int*   cnt   = (int*)  alloc((size_t)NN * 4);
    int*   cur   = (int*)  alloc((size_t)NN * 4);
    int*   rp    = (int*)  alloc((size_t)(NN + 1) * 4);
    int*   bs    = (int*)  alloc(1024 * 4);
    int*   col   = (int*)  alloc((size_t)2 * NE * 4);   // 12.8 MB
    int*   eidx  = (int*)  alloc((size_t)2 * NE * 4);   // 12.8 MB
    float* hh    = (float*)alloc((size_t)NN * NC * 4);  // 16 MB each
    float* xc    = (float*)alloc((size_t)NN * NC * 4);
    float* yb    = (float*)alloc((size_t)NN * NC * 4);
    float* S     = (float*)alloc((size_t)NN * NC * 4);
    float* xbar  = (float*)alloc((size_t)NN * NC * 4);
    float* z     = (float*)alloc((size_t)NE * NC * 4);  // 256 MB
    float* h1    = z;  // alias: h1 (102.4 MB) fully consumed by k_gemm2 before z first written

    hipMemsetAsync(cnt, 0, (size_t)NN * 4, stream);
    hipMemsetAsync(cur, 0, (size_t)NN * 4, stream);
    k_hist<<<(NE + 255) / 256, 256, 0, stream>>>(src, dst, cnt);
    int nb = (NN + 1023) / 1024;
    k_scan1<<<nb, 1024, 0, stream>>>(cnt, rp, bs);
    k_scan2<<<1, 64, 0, stream>>>(bs, nb);
    k_scan3<<<nb, 1024, 0, stream>>>(rp, bs);
    k_dis<<<(NN + 255) / 256, 256, 0, stream>>>(cnt, dis);
    k_fill<<<(NE + 255) / 256, 256, 0, stream>>>(src, dst, rp, cur, col, eidx);

    k_gemm1<<<dim3((NN + 127) / 128, HID / 128), 256, 0, stream>>>(x, W1, h1);
    k_gemm2<<<(NN + 3) / 4, 256, 0, stream>>>(h1, W2, hh, xc);

    hipMemsetAsync(S, 0, (size_t)NN * NC * 4, stream);   // S(z=0) = 0 for t=0
    for (int t = 0; t < KIT; t++) {
        k_ynew<<<(NN + 3) / 4, 256, 0, stream>>>(rp, col, dis, xc, hh, S, yb, xbar);
        k_zup<<<(NE + 255) / 256, 256, 0, stream>>>(src, dst, dis, xbar, z, t > 0 ? 1 : 0);
        k_scx<<<(NN + 3) / 4, 256, 0, stream>>>(rp, eidx, z, yb, dis, S, xc);
    }
    k_lsm<<<(NN + 3) / 4, 256, 0, stream>>>(xc, out);
}

// Round 4
// 5500.550 us; speedup vs baseline: 1.1450x; 1.1450x over previous
//
#include <hip/hip_runtime.h>
#include <hip/hip_fp16.h>
#include <math.h>

#define NN 100000
#define NE 1600000
#define FIN 500
#define HID 256
#define NC 40
#define KIT 5
#define L1P 3.0f
#define GAM 0.25f
#define BET 2.0f
#define OMG 0.75f   // 1 - gamma

// ---------------- CSR build ----------------
__global__ void k_hist(const int* __restrict__ s, const int* __restrict__ d, int* c) {
    int e = blockIdx.x * 256 + threadIdx.x;
    if (e < NE) { atomicAdd(&c[s[e]], 1); atomicAdd(&c[d[e]], 1); }
}

__global__ void k_scan1(const int* __restrict__ cnt, int* rp, int* bs) {
    __shared__ int sm[1024];
    int i = blockIdx.x * 1024 + threadIdx.x;
    int v = (i < NN) ? cnt[i] : 0;
    sm[threadIdx.x] = v;
    __syncthreads();
    for (int off = 1; off < 1024; off <<= 1) {
        int t = (threadIdx.x >= off) ? sm[threadIdx.x - off] : 0;
        __syncthreads();
        sm[threadIdx.x] += t;
        __syncthreads();
    }
    if (i < NN) rp[i] = sm[threadIdx.x] - v;   // exclusive within block
    if (threadIdx.x == 1023) bs[blockIdx.x] = sm[1023];
}

__global__ void k_scan2(int* bs, int nb) {
    if (threadIdx.x == 0 && blockIdx.x == 0) {
        int run = 0;
        for (int j = 0; j < nb; j++) { int t = bs[j]; bs[j] = run; run += t; }
    }
}

__global__ void k_scan3(int* rp, const int* __restrict__ bs) {
    int i = blockIdx.x * 1024 + threadIdx.x;
    if (i < NN) rp[i] += bs[blockIdx.x];
    if (i == 0) rp[NN] = 2 * NE;
}

__global__ void k_dis(const int* __restrict__ cnt, float* __restrict__ dis) {
    int n = blockIdx.x * 256 + threadIdx.x;
    if (n < NN) dis[n] = rsqrtf((float)cnt[n] + 1.0f);
}

// adjacency CSR (col) + incidence CSR (eidx: edge_id<<1 | is_dst)
__global__ void k_fill(const int* __restrict__ s, const int* __restrict__ d,
                       const int* __restrict__ rp, int* cur, int* col, int* eidx) {
    int e = blockIdx.x * 256 + threadIdx.x;
    if (e < NE) {
        int a = s[e], b = d[e];
        int p = rp[a] + atomicAdd(&cur[a], 1); col[p] = b; eidx[p] = (e << 1);
        int q = rp[b] + atomicAdd(&cur[b], 1); col[q] = a; eidx[q] = (e << 1) | 1;
    }
}

// ---------------- MLP ----------------
// h1 = relu(x @ W1); fp32 tiled GEMM, 128x128 tile, BK=8, 8x8 microtile
__global__ __launch_bounds__(256) void k_gemm1(const float* __restrict__ X,
                                               const float* __restrict__ W1,
                                               float* __restrict__ H1) {
    __shared__ float As[8][128];
    __shared__ float Bs[8][128];
    const int t = threadIdx.x;
    const int rblk = blockIdx.x * 128;
    const int cblk = blockIdx.y * 128;
    const int tx = t & 15, ty = t >> 4;
    const int lar = t >> 1, lak = (t & 1) * 4;     // A loader: row, k-offset
    const int lbk = t >> 5, lbc = (t & 31) * 4;    // B loader: k, col
    float acc[8][8];
    #pragma unroll
    for (int i = 0; i < 8; i++)
        #pragma unroll
        for (int j = 0; j < 8; j++) acc[i][j] = 0.f;

    for (int k0 = 0; k0 < FIN; k0 += 8) {
        float4 av = make_float4(0.f, 0.f, 0.f, 0.f);
        int row = rblk + lar;
        if (row < NN) {
            if (k0 + lak + 4 <= FIN) {
                av = *(const float4*)(X + (size_t)row * FIN + k0 + lak);
            } else {
                float tv[4] = {0.f, 0.f, 0.f, 0.f};
                #pragma unroll
                for (int j = 0; j < 4; j++)
                    if (k0 + lak + j < FIN) tv[j] = X[(size_t)row * FIN + k0 + lak + j];
                av = make_float4(tv[0], tv[1], tv[2], tv[3]);
            }
        }
        As[lak + 0][lar] = av.x; As[lak + 1][lar] = av.y;
        As[lak + 2][lar] = av.z; As[lak + 3][lar] = av.w;

        float4 bv = make_float4(0.f, 0.f, 0.f, 0.f);
        if (k0 + lbk < FIN) bv = *(const float4*)(W1 + (size_t)(k0 + lbk) * HID + cblk + lbc);
        *(float4*)&Bs[lbk][lbc] = bv;
        __syncthreads();

        #pragma unroll
        for (int kk = 0; kk < 8; kk++) {
            float aF[8], bF[8];
            *(float4*)&aF[0] = *(const float4*)&As[kk][ty * 4];
            *(float4*)&aF[4] = *(const float4*)&As[kk][64 + ty * 4];
            *(float4*)&bF[0] = *(const float4*)&Bs[kk][tx * 4];
            *(float4*)&bF[4] = *(const float4*)&Bs[kk][64 + tx * 4];
            #pragma unroll
            for (int i = 0; i < 8; i++)
                #pragma unroll
                for (int j = 0; j < 8; j++)
                    acc[i][j] = fmaf(aF[i], bF[j], acc[i][j]);
        }
        __syncthreads();
    }

    #pragma unroll
    for (int i = 0; i < 8; i++) {
        int row = rblk + ((i < 4) ? (ty * 4 + i) : (64 + ty * 4 + (i - 4)));
        if (row < NN) {
            float4 v0, v1;
            v0.x = fmaxf(acc[i][0], 0.f); v0.y = fmaxf(acc[i][1], 0.f);
            v0.z = fmaxf(acc[i][2], 0.f); v0.w = fmaxf(acc[i][3], 0.f);
            v1.x = fmaxf(acc[i][4], 0.f); v1.y = fmaxf(acc[i][5], 0.f);
            v1.z = fmaxf(acc[i][6], 0.f); v1.w = fmaxf(acc[i][7], 0.f);
            *(float4*)(H1 + (size_t)row * HID + cblk + tx * 4) = v0;
            *(float4*)(H1 + (size_t)row * HID + cblk + 64 + tx * 4) = v1;
        }
    }
}

// hh = h1 @ W2 ; also xc = hh. Wave per node, lanes = classes.
__global__ __launch_bounds__(256) void k_gemm2(const float* __restrict__ H1,
                                               const float* __restrict__ W2,
                                               float* __restrict__ hh, float* __restrict__ xc) {
    __shared__ float w2s[HID * NC];   // 40 KB
    for (int i = threadIdx.x; i < HID * NC; i += 256) w2s[i] = W2[i];
    __syncthreads();
    int wave = threadIdx.x >> 6, lane = threadIdx.x & 63;
    int n = blockIdx.x * 4 + wave;
    if (n >= NN) return;
    if (lane < NC) {
        const float* hr = H1 + (size_t)n * HID;
        float acc = 0.f;
        #pragma unroll 4
        for (int k = 0; k < HID; k += 4) {
            float4 h4 = *(const float4*)(hr + k);
            acc = fmaf(h4.x, w2s[(k + 0) * NC + lane], acc);
            acc = fmaf(h4.y, w2s[(k + 1) * NC + lane], acc);
            acc = fmaf(h4.z, w2s[(k + 2) * NC + lane], acc);
            acc = fmaf(h4.w, w2s[(k + 3) * NC + lane], acc);
        }
        hh[(size_t)n * NC + lane] = acc;
        xc[(size_t)n * NC + lane] = acc;
    }
}

// ---------------- iteration kernels ----------------
// Fused: y = gamma*hh + omega*dis*(dis*xc + sum_nbr dis_c*xc_c);  xbar = y - gamma*dis*S_prev
__global__ __launch_bounds__(256) void k_ynew(const int* __restrict__ rp, const int* __restrict__ col,
                                              const float* __restrict__ dis, const float* __restrict__ xc,
                                              const float* __restrict__ hh, const float* __restrict__ S,
                                              float* __restrict__ y, float* __restrict__ xbar) {
    int wave = threadIdx.x >> 6, lane = threadIdx.x & 63;
    int n = blockIdx.x * 4 + wave;
    if (n >= NN) return;
    int s = rp[n], e = rp[n + 1];
    if (lane < NC) {
        size_t base = (size_t)n * NC + lane;
        float dn = dis[n];
        float acc = dn * xc[base];                 // self-loop term (dis^2*xc, dn factored out)
        for (int p = s; p < e; p++) {
            int c = col[p];
            acc = fmaf(dis[c], xc[(size_t)c * NC + lane], acc);
        }
        float yv = GAM * hh[base] + OMG * dn * acc;
        y[base] = yv;
        xbar[base] = yv - GAM * dn * S[base];
    }
}

// z = prox_L21(z + beta*inc(x_bar)); WAVE per edge, lane = class. z stored fp16.
__global__ __launch_bounds__(256) void k_zup(const int* __restrict__ src, const int* __restrict__ dst,
                                             const float* __restrict__ dis, const float* __restrict__ xb,
                                             __half* __restrict__ z, int use_z) {
    int wid = (blockIdx.x * 256 + threadIdx.x) >> 6;   // one wave per edge
    int lane = threadIdx.x & 63;
    if (wid >= NE) return;
    int a = src[wid], b = dst[wid];                    // wave-uniform scalar loads
    float da = dis[a], db = dis[b];
    float zb = 0.f;
    if (lane < NC) {
        float xav = xb[(size_t)a * NC + lane];         // coalesced: 40 consecutive floats
        float xvv = xb[(size_t)b * NC + lane];
        float zv = use_z ? __half2float(z[(size_t)wid * NC + lane]) : 0.f;
        zb = zv + BET * (da * xav - db * xvv);
    }
    float n2 = zb * zb;
    #pragma unroll
    for (int off = 1; off < 64; off <<= 1) n2 += __shfl_xor(n2, off);
    float rn = sqrtf(n2);
    float scale = (rn > L1P) ? (L1P / rn) : 1.0f;
    if (lane < NC) z[(size_t)wid * NC + lane] = __float2half_rn(zb * scale);
}

// Fused: S[n] = sum_{p in incidence} sign_p * z[eid_p];  xc = y - gamma*dis*S  (z fp16)
__global__ __launch_bounds__(256) void k_scx(const int* __restrict__ rp, const int* __restrict__ eidx,
                                             const __half* __restrict__ z, const float* __restrict__ y,
                                             const float* __restrict__ dis,
                                             float* __restrict__ S, float* __restrict__ xc) {
    int wave = threadIdx.x >> 6, lane = threadIdx.x & 63;
    int n = blockIdx.x * 4 + wave;
    if (n >= NN) return;
    int s = rp[n], e = rp[n + 1];
    if (lane < NC) {
        float acc = 0.f;
        for (int p = s; p < e; p++) {
            int pk = eidx[p];
            float v = __half2float(z[(size_t)(pk >> 1) * NC + lane]);
            acc += (pk & 1) ? -v : v;
        }
        size_t base = (size_t)n * NC + lane;
        S[base] = acc;
        xc[base] = y[base] - GAM * dis[n] * acc;
    }
}

__global__ __launch_bounds__(256) void k_lsm(const float* __restrict__ xc, float* __restrict__ out) {
    int wave = threadIdx.x >> 6, lane = threadIdx.x & 63;
    int n = blockIdx.x * 4 + wave;
    if (n >= NN) return;
    float v = (lane < NC) ? xc[(size_t)n * NC + lane] : -INFINITY;
    float m = v;
    #pragma unroll
    for (int off = 1; off < 64; off <<= 1) m = fmaxf(m, __shfl_xor(m, off));
    float ex = (lane < NC) ? expf(v - m) : 0.f;
    float ssum = ex;
    #pragma unroll
    for (int off = 1; off < 64; off <<= 1) ssum += __shfl_xor(ssum, off);
    if (lane < NC) out[(size_t)n * NC + lane] = v - m - logf(ssum);
}

// ---------------- launch ----------------
extern "C" void kernel_launch(void* const* d_in, const int* in_sizes, int n_in,
                              void* d_out, int out_size, void* d_ws, size_t ws_size,
                              hipStream_t stream) {
    const float* x  = (const float*)d_in[0];
    const float* W1 = (const float*)d_in[1];
    const float* W2 = (const float*)d_in[2];
    const int* src  = (const int*)d_in[3];
    const int* dst  = (const int*)d_in[4];
    float* out = (float*)d_out;

    char* w = (char*)d_ws;
    auto alloc = [&](size_t bytes) { char* p = w; w += (bytes + 255) & ~(size_t)255; return p; };
    float* dis   = (float*)alloc((size_t)NN * 4);
    int*   cnt   = (int*)  alloc((size_t)NN * 4);
    int*   cur   = (int*)  alloc((size_t)NN * 4);
    int*   rp    = (int*)  alloc((size_t)(NN + 1) * 4);
    int*   bs    = (int*)  alloc(1024 * 4);
    int*   col   = (int*)  alloc((size_t)2 * NE * 4);   // 12.8 MB
    int*   eidx  = (int*)  alloc((size_t)2 * NE * 4);   // 12.8 MB
    float* hh    = (float*)alloc((size_t)NN * NC * 4);  // 16 MB each
    float* xc    = (float*)alloc((size_t)NN * NC * 4);
    float* yb    = (float*)alloc((size_t)NN * NC * 4);
    float* S     = (float*)alloc((size_t)NN * NC * 4);
    float* xbar  = (float*)alloc((size_t)NN * NC * 4);
    __half* z    = (__half*)alloc((size_t)NE * NC * 2); // 128 MB (fp16)
    float* h1    = (float*)z;  // alias: h1 (102.4 MB) fully consumed by k_gemm2 before z first written

    hipMemsetAsync(cnt, 0, (size_t)NN * 4, stream);
    hipMemsetAsync(cur, 0, (size_t)NN * 4, stream);
    k_hist<<<(NE + 255) / 256, 256, 0, stream>>>(src, dst, cnt);
    int nb = (NN + 1023) / 1024;
    k_scan1<<<nb, 1024, 0, stream>>>(cnt, rp, bs);
    k_scan2<<<1, 64, 0, stream>>>(bs, nb);
    k_scan3<<<nb, 1024, 0, stream>>>(rp, bs);
    k_dis<<<(NN + 255) / 256, 256, 0, stream>>>(cnt, dis);
    k_fill<<<(NE + 255) / 256, 256, 0, stream>>>(src, dst, rp, cur, col, eidx);

    k_gemm1<<<dim3((NN + 127) / 128, HID / 128), 256, 0, stream>>>(x, W1, h1);
    k_gemm2<<<(NN + 3) / 4, 256, 0, stream>>>(h1, W2, hh, xc);

    hipMemsetAsync(S, 0, (size_t)NN * NC * 4, stream);   // S(z=0) = 0 for t=0
    for (int t = 0; t < KIT; t++) {
        k_ynew<<<(NN + 3) / 4, 256, 0, stream>>>(rp, col, dis, xc, hh, S, yb, xbar);
        k_zup<<<(NE + 3) / 4, 256, 0, stream>>>(src, dst, dis, xbar, z, t > 0 ? 1 : 0);
        k_scx<<<(NN + 3) / 4, 256, 0, stream>>>(rp, eidx, z, yb, dis, S, xc);
    }
    k_lsm<<<(NN + 3) / 4, 256, 0, stream>>>(xc, out);
}

// Round 5
// 4314.288 us; speedup vs baseline: 1.4599x; 1.2750x over previous
//
#include <hip/hip_runtime.h>
#include <hip/hip_fp16.h>
#include <math.h>

#define NN 100000
#define NE 1600000
#define FIN 500
#define HID 256
#define NC 40
#define KIT 5
#define L1P 3.0f
#define GAM 0.25f
#define BET 2.0f
#define OMG 0.75f   // 1 - gamma
#define PAD 64      // fp16 shadow row stride (128 B = one cache line)

// ---------------- CSR build ----------------
__global__ void k_hist(const int* __restrict__ s, const int* __restrict__ d, int* c) {
    int e = blockIdx.x * 256 + threadIdx.x;
    if (e < NE) { atomicAdd(&c[s[e]], 1); atomicAdd(&c[d[e]], 1); }
}

__global__ void k_scan1(const int* __restrict__ cnt, int* rp, int* bs) {
    __shared__ int sm[1024];
    int i = blockIdx.x * 1024 + threadIdx.x;
    int v = (i < NN) ? cnt[i] : 0;
    sm[threadIdx.x] = v;
    __syncthreads();
    for (int off = 1; off < 1024; off <<= 1) {
        int t = (threadIdx.x >= off) ? sm[threadIdx.x - off] : 0;
        __syncthreads();
        sm[threadIdx.x] += t;
        __syncthreads();
    }
    if (i < NN) rp[i] = sm[threadIdx.x] - v;   // exclusive within block
    if (threadIdx.x == 1023) bs[blockIdx.x] = sm[1023];
}

__global__ void k_scan2(int* bs, int nb) {
    if (threadIdx.x == 0 && blockIdx.x == 0) {
        int run = 0;
        for (int j = 0; j < nb; j++) { int t = bs[j]; bs[j] = run; run += t; }
    }
}

__global__ void k_scan3(int* rp, const int* __restrict__ bs) {
    int i = blockIdx.x * 1024 + threadIdx.x;
    if (i < NN) rp[i] += bs[blockIdx.x];
    if (i == 0) rp[NN] = 2 * NE;
}

__global__ void k_dis(const int* __restrict__ cnt, float* __restrict__ dis) {
    int n = blockIdx.x * 256 + threadIdx.x;
    if (n < NN) dis[n] = rsqrtf((float)cnt[n] + 1.0f);
}

// adjacency CSR (col) only — z is never gathered anymore
__global__ void k_fill(const int* __restrict__ s, const int* __restrict__ d,
                       const int* __restrict__ rp, int* cur, int* col) {
    int e = blockIdx.x * 256 + threadIdx.x;
    if (e < NE) {
        int a = s[e], b = d[e];
        int p = rp[a] + atomicAdd(&cur[a], 1); col[p] = b;
        int q = rp[b] + atomicAdd(&cur[b], 1); col[q] = a;
    }
}

// ---------------- MLP ----------------
// h1 = relu(x @ W1); fp32 tiled GEMM, 128x128 tile, BK=8, 8x8 microtile
__global__ __launch_bounds__(256) void k_gemm1(const float* __restrict__ X,
                                               const float* __restrict__ W1,
                                               float* __restrict__ H1) {
    __shared__ float As[8][128];
    __shared__ float Bs[8][128];
    const int t = threadIdx.x;
    const int rblk = blockIdx.x * 128;
    const int cblk = blockIdx.y * 128;
    const int tx = t & 15, ty = t >> 4;
    const int lar = t >> 1, lak = (t & 1) * 4;     // A loader: row, k-offset
    const int lbk = t >> 5, lbc = (t & 31) * 4;    // B loader: k, col
    float acc[8][8];
    #pragma unroll
    for (int i = 0; i < 8; i++)
        #pragma unroll
        for (int j = 0; j < 8; j++) acc[i][j] = 0.f;

    for (int k0 = 0; k0 < FIN; k0 += 8) {
        float4 av = make_float4(0.f, 0.f, 0.f, 0.f);
        int row = rblk + lar;
        if (row < NN) {
            if (k0 + lak + 4 <= FIN) {
                av = *(const float4*)(X + (size_t)row * FIN + k0 + lak);
            } else {
                float tv[4] = {0.f, 0.f, 0.f, 0.f};
                #pragma unroll
                for (int j = 0; j < 4; j++)
                    if (k0 + lak + j < FIN) tv[j] = X[(size_t)row * FIN + k0 + lak + j];
                av = make_float4(tv[0], tv[1], tv[2], tv[3]);
            }
        }
        As[lak + 0][lar] = av.x; As[lak + 1][lar] = av.y;
        As[lak + 2][lar] = av.z; As[lak + 3][lar] = av.w;

        float4 bv = make_float4(0.f, 0.f, 0.f, 0.f);
        if (k0 + lbk < FIN) bv = *(const float4*)(W1 + (size_t)(k0 + lbk) * HID + cblk + lbc);
        *(float4*)&Bs[lbk][lbc] = bv;
        __syncthreads();

        #pragma unroll
        for (int kk = 0; kk < 8; kk++) {
            float aF[8], bF[8];
            *(float4*)&aF[0] = *(const float4*)&As[kk][ty * 4];
            *(float4*)&aF[4] = *(const float4*)&As[kk][64 + ty * 4];
            *(float4*)&bF[0] = *(const float4*)&Bs[kk][tx * 4];
            *(float4*)&bF[4] = *(const float4*)&Bs[kk][64 + tx * 4];
            #pragma unroll
            for (int i = 0; i < 8; i++)
                #pragma unroll
                for (int j = 0; j < 8; j++)
                    acc[i][j] = fmaf(aF[i], bF[j], acc[i][j]);
        }
        __syncthreads();
    }

    #pragma unroll
    for (int i = 0; i < 8; i++) {
        int row = rblk + ((i < 4) ? (ty * 4 + i) : (64 + ty * 4 + (i - 4)));
        if (row < NN) {
            float4 v0, v1;
            v0.x = fmaxf(acc[i][0], 0.f); v0.y = fmaxf(acc[i][1], 0.f);
            v0.z = fmaxf(acc[i][2], 0.f); v0.w = fmaxf(acc[i][3], 0.f);
            v1.x = fmaxf(acc[i][4], 0.f); v1.y = fmaxf(acc[i][5], 0.f);
            v1.z = fmaxf(acc[i][6], 0.f); v1.w = fmaxf(acc[i][7], 0.f);
            *(float4*)(H1 + (size_t)row * HID + cblk + tx * 4) = v0;
            *(float4*)(H1 + (size_t)row * HID + cblk + 64 + tx * 4) = v1;
        }
    }
}

// hh = h1 @ W2 ; xc = hh ; xg = dis*hh (fp16 shadow). Wave per node, lanes = classes.
__global__ __launch_bounds__(256) void k_gemm2(const float* __restrict__ H1,
                                               const float* __restrict__ W2,
                                               const float* __restrict__ dis,
                                               float* __restrict__ hh, float* __restrict__ xc,
                                               __half* __restrict__ xg) {
    __shared__ float w2s[HID * NC];   // 40 KB
    for (int i = threadIdx.x; i < HID * NC; i += 256) w2s[i] = W2[i];
    __syncthreads();
    int wave = threadIdx.x >> 6, lane = threadIdx.x & 63;
    int n = blockIdx.x * 4 + wave;
    if (n >= NN) return;
    if (lane < NC) {
        const float* hr = H1 + (size_t)n * HID;
        float acc = 0.f;
        #pragma unroll 4
        for (int k = 0; k < HID; k += 4) {
            float4 h4 = *(const float4*)(hr + k);
            acc = fmaf(h4.x, w2s[(k + 0) * NC + lane], acc);
            acc = fmaf(h4.y, w2s[(k + 1) * NC + lane], acc);
            acc = fmaf(h4.z, w2s[(k + 2) * NC + lane], acc);
            acc = fmaf(h4.w, w2s[(k + 3) * NC + lane], acc);
        }
        hh[(size_t)n * NC + lane] = acc;
        xc[(size_t)n * NC + lane] = acc;
        xg[(size_t)n * PAD + lane] = __float2half_rn(dis[n] * acc);
    }
}

// ---------------- iteration kernels ----------------
// Fused: y = gamma*hh + omega*dn*(dn*xc + sum_nbr xg_c);  xbs = dn*(y - gamma*dn*S_prev) fp16
// xg rows are premultiplied by dis and padded to one cache line; 4x unrolled gather for MLP.
__global__ __launch_bounds__(256) void k_ynew(const int* __restrict__ rp, const int* __restrict__ col,
                                              const float* __restrict__ dis, const float* __restrict__ xc,
                                              const float* __restrict__ hh, const float* __restrict__ S,
                                              const __half* __restrict__ xg,
                                              float* __restrict__ y, __half* __restrict__ xbs) {
    int wave = threadIdx.x >> 6, lane = threadIdx.x & 63;
    int n = blockIdx.x * 4 + wave;
    if (n >= NN) return;
    int s = rp[n], e = rp[n + 1];
    if (lane < NC) {
        size_t base = (size_t)n * NC + lane;
        float dn = dis[n];
        float acc = dn * xc[base];                 // self-loop term
        int p = s;
        for (; p + 3 < e; p += 4) {                // 4 independent line-gathers in flight
            int c0 = col[p], c1 = col[p + 1], c2 = col[p + 2], c3 = col[p + 3];
            float v0 = __half2float(xg[(size_t)c0 * PAD + lane]);
            float v1 = __half2float(xg[(size_t)c1 * PAD + lane]);
            float v2 = __half2float(xg[(size_t)c2 * PAD + lane]);
            float v3 = __half2float(xg[(size_t)c3 * PAD + lane]);
            acc += (v0 + v1) + (v2 + v3);
        }
        for (; p < e; p++)
            acc += __half2float(xg[(size_t)col[p] * PAD + lane]);
        float yv = GAM * hh[base] + OMG * dn * acc;
        y[base] = yv;
        xbs[(size_t)n * PAD + lane] = __float2half_rn(dn * (yv - GAM * dn * S[base]));
    }
}

// z = prox_L21(z + beta*(xbs[a] - xbs[b])); wave per edge; scatter +/-z into S via atomics.
__global__ __launch_bounds__(256) void k_zup(const int* __restrict__ src, const int* __restrict__ dst,
                                             const __half* __restrict__ xbs,
                                             __half* __restrict__ z, float* __restrict__ S, int use_z) {
    int wid = (blockIdx.x * 256 + threadIdx.x) >> 6;   // one wave per edge
    int lane = threadIdx.x & 63;
    if (wid >= NE) return;
    int a = src[wid], b = dst[wid];                    // wave-uniform loads
    float zb = 0.f;
    if (lane < NC) {
        float ia = __half2float(xbs[(size_t)a * PAD + lane]);   // one line each
        float ib = __half2float(xbs[(size_t)b * PAD + lane]);
        float zv = use_z ? __half2float(z[(size_t)wid * NC + lane]) : 0.f;
        zb = zv + BET * (ia - ib);
    }
    float n2 = zb * zb;
    #pragma unroll
    for (int off = 1; off < 64; off <<= 1) n2 += __shfl_xor(n2, off);
    float rn = sqrtf(n2);
    float scale = (rn > L1P) ? (L1P / rn) : 1.0f;
    if (lane < NC) {
        float v = zb * scale;
        z[(size_t)wid * NC + lane] = __float2half_rn(v);
        atomicAdd(S + (size_t)a * NC + lane, v);
        atomicAdd(S + (size_t)b * NC + lane, -v);
    }
}

// Elementwise: xc = y - gamma*dis*S ; xg = dis*xc (fp16 shadow)
__global__ __launch_bounds__(256) void k_scx(const float* __restrict__ y, const float* __restrict__ S,
                                             const float* __restrict__ dis,
                                             float* __restrict__ xc, __half* __restrict__ xg) {
    int wave = threadIdx.x >> 6, lane = threadIdx.x & 63;
    int n = blockIdx.x * 4 + wave;
    if (n >= NN) return;
    if (lane < NC) {
        size_t base = (size_t)n * NC + lane;
        float dn = dis[n];
        float v = y[base] - GAM * dn * S[base];
        xc[base] = v;
        xg[(size_t)n * PAD + lane] = __float2half_rn(dn * v);
    }
}

__global__ __launch_bounds__(256) void k_lsm(const float* __restrict__ xc, float* __restrict__ out) {
    int wave = threadIdx.x >> 6, lane = threadIdx.x & 63;
    int n = blockIdx.x * 4 + wave;
    if (n >= NN) return;
    float v = (lane < NC) ? xc[(size_t)n * NC + lane] : -INFINITY;
    float m = v;
    #pragma unroll
    for (int off = 1; off < 64; off <<= 1) m = fmaxf(m, __shfl_xor(m, off));
    float ex = (lane < NC) ? expf(v - m) : 0.f;
    float ssum = ex;
    #pragma unroll
    for (int off = 1; off < 64; off <<= 1) ssum += __shfl_xor(ssum, off);
    if (lane < NC) out[(size_t)n * NC + lane] = v - m - logf(ssum);
}

// ---------------- launch ----------------
extern "C" void kernel_launch(void* const* d_in, const int* in_sizes, int n_in,
                              void* d_out, int out_size, void* d_ws, size_t ws_size,
                              hipStream_t stream) {
    const float* x  = (const float*)d_in[0];
    const float* W1 = (const float*)d_in[1];
    const float* W2 = (const float*)d_in[2];
    const int* src  = (const int*)d_in[3];
    const int* dst  = (const int*)d_in[4];
    float* out = (float*)d_out;

    char* w = (char*)d_ws;
    auto alloc = [&](size_t bytes) { char* p = w; w += (bytes + 255) & ~(size_t)255; return p; };
    float* dis   = (float*)alloc((size_t)NN * 4);
    int*   cnt   = (int*)  alloc((size_t)NN * 4);
    int*   cur   = (int*)  alloc((size_t)NN * 4);
    int*   rp    = (int*)  alloc((size_t)(NN + 1) * 4);
    int*   bs    = (int*)  alloc(1024 * 4);
    int*   col   = (int*)  alloc((size_t)2 * NE * 4);    // 12.8 MB
    float* hh    = (float*)alloc((size_t)NN * NC * 4);   // 16 MB each
    float* xc    = (float*)alloc((size_t)NN * NC * 4);
    float* yb    = (float*)alloc((size_t)NN * NC * 4);
    float* S     = (float*)alloc((size_t)NN * NC * 4);
    __half* xg   = (__half*)alloc((size_t)NN * PAD * 2); // 12.8 MB, dis*xc shadow
    __half* xbs  = (__half*)alloc((size_t)NN * PAD * 2); // 12.8 MB, dis*xbar shadow
    __half* z    = (__half*)alloc((size_t)NE * NC * 2);  // 128 MB (fp16)
    float* h1    = (float*)z;  // alias: h1 (102.4 MB) fully consumed by k_gemm2 before z first written

    hipMemsetAsync(cnt, 0, (size_t)NN * 4, stream);
    hipMemsetAsync(cur, 0, (size_t)NN * 4, stream);
    k_hist<<<(NE + 255) / 256, 256, 0, stream>>>(src, dst, cnt);
    int nb = (NN + 1023) / 1024;
    k_scan1<<<nb, 1024, 0, stream>>>(cnt, rp, bs);
    k_scan2<<<1, 64, 0, stream>>>(bs, nb);
    k_scan3<<<nb, 1024, 0, stream>>>(rp, bs);
    k_dis<<<(NN + 255) / 256, 256, 0, stream>>>(cnt, dis);
    k_fill<<<(NE + 255) / 256, 256, 0, stream>>>(src, dst, rp, cur, col);

    k_gemm1<<<dim3((NN + 127) / 128, HID / 128), 256, 0, stream>>>(x, W1, h1);
    k_gemm2<<<(NN + 3) / 4, 256, 0, stream>>>(h1, W2, dis, hh, xc, xg);

    hipMemsetAsync(S, 0, (size_t)NN * NC * 4, stream);   // S(z=0)=0 for t=0 ynew
    for (int t = 0; t < KIT; t++) {
        k_ynew<<<(NN + 3) / 4, 256, 0, stream>>>(rp, col, dis, xc, hh, S, xg, yb, xbs);
        hipMemsetAsync(S, 0, (size_t)NN * NC * 4, stream);
        k_zup<<<(NE + 3) / 4, 256, 0, stream>>>(src, dst, xbs, z, S, t > 0 ? 1 : 0);
        k_scx<<<(NN + 3) / 4, 256, 0, stream>>>(yb, S, dis, xc, xg);
    }
    k_lsm<<<(NN + 3) / 4, 256, 0, stream>>>(xc, out);
}